// Round 4
// baseline (868.425 us; speedup 1.0000x reference)
//
#include <hip/hip_runtime.h>
#include <cstddef>

#define NN 50000
#define NE 800000
#define D 128
#define BN_EPS 1e-5f

typedef __attribute__((ext_vector_type(8))) short bf16x8;
typedef __attribute__((ext_vector_type(4))) float f32x4;

union FragU { int4 i; bf16x8 v; };

__device__ __forceinline__ unsigned short f2bf(float x) {
    unsigned u = __float_as_uint(x);
    return (unsigned short)((u + 0x7fffu + ((u >> 16) & 1u)) >> 16);  // RNE
}
__device__ __forceinline__ float bf2f(unsigned short b) {
    return __uint_as_float(((unsigned)b) << 16);
}
__device__ __forceinline__ unsigned pk2(float a, float b) {
    return (unsigned)f2bf(a) | ((unsigned)f2bf(b) << 16);
}

// ---------------------------------------------------------------------------
// W prep: W[k][n] f32 -> fragment-linear bf16 Wt (verified R2: B-operand frag)
// Wt[((ct*4+ks)*64 + l)*8 + j] = bf16( W[(32ks + (l>>4)*8 + j)*128 + 16ct + (l&15)] )
// ---------------------------------------------------------------------------
__global__ __launch_bounds__(256) void wprep_kernel(
    const float* __restrict__ W, unsigned short* __restrict__ Wt)
{
    const int idx = blockIdx.x * 256 + threadIdx.x;   // [0, 16384)
    const int j  = idx & 7;
    const int l  = (idx >> 3) & 63;
    const int ks = (idx >> 9) & 3;
    const int ct = (idx >> 11) & 7;
    const int n  = 16 * ct + (l & 15);
    const int k  = 32 * ks + ((l >> 4) << 3) + j;
    Wt[idx] = f2bf(W[k * 128 + n]);
}

// ---------------------------------------------------------------------------
// Barrier-light MFMA 2-layer MLP. 4 independent waves/block, 16 rows/wave.
// GEMM1 computed SWAPPED (Y^T = W1^T X^T) so each lane holds Y[m][.] slices
// lane-locally; GEMM1->GEMM2 transpose done with __shfl (no LDS). X fragments
// loaded straight from global. W1 frags in LDS (one barrier); W2 frags from
// L1/L2. Split-bf16 (hi+lo) for f32-grade accuracy.
// MODE 0: X = e[row]+h[src]+h[dst], rows=NE.  MODE 1: X = h[row]+agg[row].
// ---------------------------------------------------------------------------
template<int MODE>
__global__ __launch_bounds__(256, 4) void mlp_mfma_kernel(
    const float* __restrict__ h, const float* __restrict__ e_or_agg,
    const int* __restrict__ src, const int* __restrict__ dst,
    const unsigned short* __restrict__ Wt1, const float* __restrict__ b1,
    const unsigned short* __restrict__ Wt2, const float* __restrict__ b2,
    float* __restrict__ x2out, float* __restrict__ stats)
{
    __shared__ __align__(16) unsigned short W1L[16384];   // 32 KB
    __shared__ float red[1024];                           // 4 KB

    const int tid  = threadIdx.x;
    const int lane = tid & 63;
    const int w    = tid >> 6;
    const int g    = lane >> 4;
    const int m    = lane & 15;
    const long r0  = (long)blockIdx.x * 64;

    // ---- stage W1 fragments to LDS (linear copy) ----
    {
        int4* dp = (int4*)W1L;
        const int4* sp = (const int4*)Wt1;
#pragma unroll
        for (int i = 0; i < 8; ++i) dp[tid + 256 * i] = sp[tid + 256 * i];
    }
    __syncthreads();

    // ---- the lane's X-row ----
    const long rowg = r0 + 16 * w + m;
    long rowl = rowg;
    if (MODE == 1) rowl = (rowl < NN) ? rowl : (NN - 1);

    const float *pa, *pb, *pc;
    if (MODE == 0) {
        pa = e_or_agg + (size_t)rowg * D;
        pb = h + (size_t)src[rowg] * D;
        pc = h + (size_t)dst[rowg] * D;
    } else {
        pa = h + (size_t)rowl * D;
        pb = e_or_agg + (size_t)rowl * D;
        pc = nullptr;
    }

    // ---- X fragments direct from global, split hi/lo ----
    FragU xh[4], xl[4];
#pragma unroll
    for (int ks = 0; ks < 4; ++ks) {
        const int c = 32 * ks + 8 * g;
        const float4 aa = *(const float4*)(pa + c);
        const float4 ab = *(const float4*)(pa + c + 4);
        const float4 ba = *(const float4*)(pb + c);
        const float4 bb = *(const float4*)(pb + c + 4);
        float xs[8];
        xs[0] = aa.x + ba.x; xs[1] = aa.y + ba.y; xs[2] = aa.z + ba.z; xs[3] = aa.w + ba.w;
        xs[4] = ab.x + bb.x; xs[5] = ab.y + bb.y; xs[6] = ab.z + bb.z; xs[7] = ab.w + bb.w;
        if (MODE == 0) {
            const float4 ca = *(const float4*)(pc + c);
            const float4 cb = *(const float4*)(pc + c + 4);
            xs[0] += ca.x; xs[1] += ca.y; xs[2] += ca.z; xs[3] += ca.w;
            xs[4] += cb.x; xs[5] += cb.y; xs[6] += cb.z; xs[7] += cb.w;
        }
        const unsigned h0 = pk2(xs[0], xs[1]), h1 = pk2(xs[2], xs[3]);
        const unsigned h2 = pk2(xs[4], xs[5]), h3 = pk2(xs[6], xs[7]);
        xh[ks].i = make_int4(h0, h1, h2, h3);
        float lo[8];
        lo[0] = xs[0] - bf2f((unsigned short)h0);  lo[1] = xs[1] - bf2f((unsigned short)(h0 >> 16));
        lo[2] = xs[2] - bf2f((unsigned short)h1);  lo[3] = xs[3] - bf2f((unsigned short)(h1 >> 16));
        lo[4] = xs[4] - bf2f((unsigned short)h2);  lo[5] = xs[5] - bf2f((unsigned short)(h2 >> 16));
        lo[6] = xs[6] - bf2f((unsigned short)h3);  lo[7] = xs[7] - bf2f((unsigned short)(h3 >> 16));
        xl[ks].i = make_int4(pk2(lo[0], lo[1]), pk2(lo[2], lo[3]),
                             pk2(lo[4], lo[5]), pk2(lo[6], lo[7]));
    }

    // ---- GEMM1 (swapped): acc[ct] holds Y[m][16ct + 4g + r] ----
    const bf16x8* W1f = (const bf16x8*)W1L;
    f32x4 acc[8];
#pragma unroll
    for (int ct = 0; ct < 8; ++ct) acc[ct] = (f32x4){0.f, 0.f, 0.f, 0.f};
#pragma unroll
    for (int ct = 0; ct < 8; ++ct)
#pragma unroll
        for (int ks = 0; ks < 4; ++ks) {
            const bf16x8 wf = W1f[(ct * 4 + ks) * 64 + lane];
            acc[ct] = __builtin_amdgcn_mfma_f32_16x16x32_bf16(wf, xh[ks].v, acc[ct], 0, 0, 0);
            acc[ct] = __builtin_amdgcn_mfma_f32_16x16x32_bf16(wf, xl[ks].v, acc[ct], 0, 0, 0);
        }

    // ---- bias + relu + split/pack (lane-local Y slices) ----
    unsigned yh[8][2], yl[8][2];
#pragma unroll
    for (int ct = 0; ct < 8; ++ct) {
        const float4 bv = *(const float4*)(b1 + 16 * ct + 4 * g);
        const float y0 = fmaxf(acc[ct][0] + bv.x, 0.f);
        const float y1 = fmaxf(acc[ct][1] + bv.y, 0.f);
        const float y2 = fmaxf(acc[ct][2] + bv.z, 0.f);
        const float y3 = fmaxf(acc[ct][3] + bv.w, 0.f);
        yh[ct][0] = pk2(y0, y1);  yh[ct][1] = pk2(y2, y3);
        const float l0 = y0 - bf2f((unsigned short)yh[ct][0]);
        const float l1 = y1 - bf2f((unsigned short)(yh[ct][0] >> 16));
        const float l2 = y2 - bf2f((unsigned short)yh[ct][1]);
        const float l3 = y3 - bf2f((unsigned short)(yh[ct][1] >> 16));
        yl[ct][0] = pk2(l0, l1);  yl[ct][1] = pk2(l2, l3);
    }

    // ---- in-register transpose: assemble GEMM2 A-frags via shuffles ----
    // target lane (g,m), ks needs Y[m][32ks+8g+j]; sources: lanes
    // sA=32(g&1)+m (j0..3), sB=sA+16 (j4..7), source reg ct = 2ks+(g>>1).
    FragU ah[4], al[4];
    const int sA = ((g & 1) << 5) | m;
    const int sB = sA + 16;
    const bool gh = (g >> 1) != 0;
#pragma unroll
    for (int ks = 0; ks < 4; ++ks) {
        int p, q, w0, w1, w2, w3;
        p = __shfl((int)yh[2*ks][0], sA); q = __shfl((int)yh[2*ks+1][0], sA); w0 = gh ? q : p;
        p = __shfl((int)yh[2*ks][1], sA); q = __shfl((int)yh[2*ks+1][1], sA); w1 = gh ? q : p;
        p = __shfl((int)yh[2*ks][0], sB); q = __shfl((int)yh[2*ks+1][0], sB); w2 = gh ? q : p;
        p = __shfl((int)yh[2*ks][1], sB); q = __shfl((int)yh[2*ks+1][1], sB); w3 = gh ? q : p;
        ah[ks].i = make_int4(w0, w1, w2, w3);
        p = __shfl((int)yl[2*ks][0], sA); q = __shfl((int)yl[2*ks+1][0], sA); w0 = gh ? q : p;
        p = __shfl((int)yl[2*ks][1], sA); q = __shfl((int)yl[2*ks+1][1], sA); w1 = gh ? q : p;
        p = __shfl((int)yl[2*ks][0], sB); q = __shfl((int)yl[2*ks+1][0], sB); w2 = gh ? q : p;
        p = __shfl((int)yl[2*ks][1], sB); q = __shfl((int)yl[2*ks+1][1], sB); w3 = gh ? q : p;
        al[ks].i = make_int4(w0, w1, w2, w3);
    }

    // ---- GEMM2 (normal): acc2[ct] holds Z[4g+r][16ct + m]; W2 from L1/L2 ----
    const bf16x8* W2f = (const bf16x8*)Wt2;
    f32x4 acc2[8];
#pragma unroll
    for (int ct = 0; ct < 8; ++ct) acc2[ct] = (f32x4){0.f, 0.f, 0.f, 0.f};
#pragma unroll
    for (int ct = 0; ct < 8; ++ct)
#pragma unroll
        for (int ks = 0; ks < 4; ++ks) {
            const bf16x8 wf = W2f[(ct * 4 + ks) * 64 + lane];
            acc2[ct] = __builtin_amdgcn_mfma_f32_16x16x32_bf16(ah[ks].v, wf, acc2[ct], 0, 0, 0);
            acc2[ct] = __builtin_amdgcn_mfma_f32_16x16x32_bf16(al[ks].v, wf, acc2[ct], 0, 0, 0);
        }

    // ---- epilogue: bias, store, BN stats (shuffle-reduce over g) ----
#pragma unroll
    for (int ct = 0; ct < 8; ++ct) {
        const float b2c = b2[16 * ct + m];
        float s = 0.f, q = 0.f;
#pragma unroll
        for (int r = 0; r < 4; ++r) {
            const long grow = r0 + 16 * w + 4 * g + r;
            if (MODE == 0 || grow < NN) {
                const float z = acc2[ct][r] + b2c;
                x2out[(size_t)grow * D + 16 * ct + m] = z;
                s += z; q += z * z;
            }
        }
        s += __shfl_xor(s, 16); s += __shfl_xor(s, 32);
        q += __shfl_xor(q, 16); q += __shfl_xor(q, 32);
        if (g == 0) {
            red[w * 128 + 16 * ct + m]       = s;
            red[512 + w * 128 + 16 * ct + m] = q;
        }
    }
    __syncthreads();
    if (tid < 128) {
        const float s = red[tid] + red[128 + tid] + red[256 + tid] + red[384 + tid];
        const float q = red[512 + tid] + red[640 + tid] + red[768 + tid] + red[896 + tid];
        unsafeAtomicAdd(&stats[tid], s);
        unsafeAtomicAdd(&stats[128 + tid], q);
    }
}

// stats layout: [0:128) sum, [128:256) sumsq, [256:384) scale, [384:512) shift
__global__ void bn_finalize_kernel(float* __restrict__ stats,
                                   const float* __restrict__ gamma,
                                   const float* __restrict__ beta,
                                   float inv_count)
{
    const int c = threadIdx.x;
    if (c < D) {
        const float mu  = stats[c] * inv_count;
        const float var = stats[128 + c] * inv_count - mu * mu;
        const float sc  = rsqrtf(var + BN_EPS) * gamma[c];
        stats[256 + c] = sc;
        stats[384 + c] = beta[c] - mu * sc;
    }
}

// ---- CSR build ----
__global__ __launch_bounds__(256) void hist_kernel(
    const int* __restrict__ dst, int* __restrict__ cnt)
{
    const int i = blockIdx.x * 256 + threadIdx.x;
    if (i < NE) atomicAdd(&cnt[dst[i]], 1);
}

__global__ __launch_bounds__(1024) void scan_kernel(
    const int* __restrict__ cnt, int* __restrict__ off)
{
    __shared__ int part[1024];
    const int t = threadIdx.x;
    const int SEG = (NN + 1023) / 1024;
    const int base = t * SEG;

    int s = 0;
    for (int i = 0; i < SEG; ++i) {
        const int idx = base + i;
        if (idx < NN) s += cnt[idx];
    }
    part[t] = s;
    __syncthreads();
    for (int d = 1; d < 1024; d <<= 1) {
        int v = (t >= d) ? part[t - d] : 0;
        __syncthreads();
        part[t] += v;
        __syncthreads();
    }
    int run = (t > 0) ? part[t - 1] : 0;
    for (int i = 0; i < SEG; ++i) {
        const int idx = base + i;
        if (idx < NN) { off[idx] = run; run += cnt[idx]; }
    }
    if (t == 1023) off[NN] = part[1023];
}

__global__ __launch_bounds__(256) void csr_scatter_kernel(
    const int* __restrict__ dst, const int* __restrict__ off,
    int* __restrict__ cnt, int* __restrict__ csr)
{
    const int i = blockIdx.x * 256 + threadIdx.x;
    if (i < NE) {
        const int d = dst[i];
        const int p = atomicSub(&cnt[d], 1) - 1;
        csr[off[d] + p] = i;
    }
}

// ---------------------------------------------------------------------------
// Fused BN-apply + residual + segment-sum gather (one wave per node).
// ---------------------------------------------------------------------------
__global__ __launch_bounds__(256) void apply_gather_kernel(
    const float* __restrict__ e, const float* __restrict__ stats,
    const int* __restrict__ off, const int* __restrict__ csr,
    float* __restrict__ eout, float* __restrict__ agg)
{
    const int node = blockIdx.x * 4 + (threadIdx.x >> 6);
    const int lane = threadIdx.x & 63;
    const int c0   = lane * 2;
    if (node >= NN) return;

    const float2 sc = *(const float2*)(stats + 256 + c0);
    const float2 sh = *(const float2*)(stats + 384 + c0);
    float2 acc = make_float2(0.f, 0.f);
    const int jb = off[node], je = off[node + 1];
    for (int j = jb; j < je; ++j) {
        const int eidx = csr[j];
        const size_t base = (size_t)eidx * D + c0;
        const float2 x  = *(const float2*)(eout + base);
        const float2 ev = *(const float2*)(e + base);
        float2 v;
        v.x = fmaf(x.x, sc.x, sh.x) + ev.x;
        v.y = fmaf(x.y, sc.y, sh.y) + ev.y;
        *(float2*)(eout + base) = v;
        acc.x += v.x;
        acc.y += v.y;
    }
    *(float2*)(agg + (size_t)node * D + c0) = acc;
}

// h_new = y2*scale + shift + h (in-place over y2 in d_out)
__global__ __launch_bounds__(256) void node_apply_kernel(
    const float* __restrict__ h, const float* __restrict__ stats,
    float* __restrict__ hout)
{
    const int gid = blockIdx.x * 256 + threadIdx.x;
    const int c0  = (gid & 31) * 4;
    const size_t base = (size_t)(gid >> 5) * D + c0;

    const float4 sc = *(const float4*)(stats + 256 + c0);
    const float4 sh = *(const float4*)(stats + 384 + c0);
    const float4 x  = *(const float4*)(hout + base);
    const float4 hv = *(const float4*)(h + base);
    float4 v;
    v.x = fmaf(x.x, sc.x, sh.x) + hv.x;
    v.y = fmaf(x.y, sc.y, sh.y) + hv.y;
    v.z = fmaf(x.z, sc.z, sh.z) + hv.z;
    v.w = fmaf(x.w, sc.w, sh.w) + hv.w;
    *(float4*)(hout + base) = v;
}

extern "C" void kernel_launch(void* const* d_in, const int* in_sizes, int n_in,
                              void* d_out, int out_size, void* d_ws, size_t ws_size,
                              hipStream_t stream)
{
    const float* h   = (const float*)d_in[0];
    const float* e   = (const float*)d_in[1];
    const int*   src = (const int*)d_in[2];
    const int*   dst = (const int*)d_in[3];
    const float* Wa1 = (const float*)d_in[4];
    const float* ba1 = (const float*)d_in[5];
    const float* Wa2 = (const float*)d_in[6];
    const float* ba2 = (const float*)d_in[7];
    const float* Wb1 = (const float*)d_in[8];
    const float* bb1 = (const float*)d_in[9];
    const float* Wb2 = (const float*)d_in[10];
    const float* bb2 = (const float*)d_in[11];
    const float* ga  = (const float*)d_in[12];
    const float* bea = (const float*)d_in[13];
    const float* gb  = (const float*)d_in[14];
    const float* beb = (const float*)d_in[15];

    float* out  = (float*)d_out;
    float* hnew = out;                      // NN*D
    float* enew = out + (size_t)NN * D;     // NE*D (x2 scratch, then e_new)

    // ws layout (float units):
    //   estats[512] | nstats[512] | icnt[NN ints] | ioff[NN+1 ints] | pad3 |
    //   Wtb1/Wtb2/Wta1/Wta2 (4 x 16384 ushort) | csr[NE ints] | agg[NN*D]
    float* ws     = (float*)d_ws;
    float* estats = ws;
    float* nstats = ws + 512;
    int*   icnt   = (int*)(ws + 1024);
    int*   ioff   = icnt + NN;
    unsigned short* wtb1 = (unsigned short*)(ioff + NN + 1 + 3);  // 16B aligned
    unsigned short* wtb2 = wtb1 + 16384;
    unsigned short* wta1 = wtb2 + 16384;
    unsigned short* wta2 = wta1 + 16384;
    int*   icsr  = (int*)(wta2 + 16384);
    float* agg   = (float*)(icsr + NE);

    // zero BN stats + histogram counters
    hipMemsetAsync(d_ws, 0, (size_t)(1024 + NN) * sizeof(float), stream);

    // ---- weight prep (fragment-linear bf16) ----
    wprep_kernel<<<64, 256, 0, stream>>>(Wb1, wtb1);
    wprep_kernel<<<64, 256, 0, stream>>>(Wb2, wtb2);
    wprep_kernel<<<64, 256, 0, stream>>>(Wa1, wta1);
    wprep_kernel<<<64, 256, 0, stream>>>(Wa2, wta2);

    // ---- CSR build ----
    hist_kernel<<<(NE + 255) / 256, 256, 0, stream>>>(dst, icnt);
    scan_kernel<<<1, 1024, 0, stream>>>(icnt, ioff);
    csr_scatter_kernel<<<(NE + 255) / 256, 256, 0, stream>>>(dst, ioff, icnt, icsr);

    // ---- bond (edge) path ----
    mlp_mfma_kernel<0><<<NE / 64, 256, 0, stream>>>(h, e, src, dst,
                                                    wtb1, bb1, wtb2, bb2,
                                                    enew /*x2*/, estats);
    bn_finalize_kernel<<<1, 128, 0, stream>>>(estats, gb, beb, 1.0f / NE);
    apply_gather_kernel<<<(NN + 3) / 4, 256, 0, stream>>>(e, estats, ioff, icsr,
                                                          enew, agg);

    // ---- atom (node) path ----
    mlp_mfma_kernel<1><<<(NN + 63) / 64, 256, 0, stream>>>(h, agg, nullptr, nullptr,
                                                           wta1, ba1, wta2, ba2,
                                                           hnew /*y2*/, nstats);
    bn_finalize_kernel<<<1, 128, 0, stream>>>(nstats, ga, bea, 1.0f / NN);
    node_apply_kernel<<<(NN * 32) / 256, 256, 0, stream>>>(h, nstats, hnew);
}